// Round 1
// baseline (1718.842 us; speedup 1.0000x reference)
//
#include <hip/hip_runtime.h>

#define NB  262144
#define NCH 29

__device__ __forceinline__ float elu_f(float x) {
    return x > 0.0f ? x : (__expf(x) - 1.0f);
}

__device__ __forceinline__ float softplus_f(float x) {
    // log1p(exp(x)) stable form: max(x,0) + log(1 + exp(-|x|))
    return fmaxf(x, 0.0f) + __logf(1.0f + __expf(-fabsf(x)));
}

__global__ __launch_bounds__(256, 3)
void lp_kernel(const float* __restrict__ tg, const float* __restrict__ tl,
               const float* __restrict__ ti, const float* __restrict__ mu,
               const float* __restrict__ mub,
               const float* __restrict__ W1, const float* __restrict__ B1,
               const float* __restrict__ W2, const float* __restrict__ B2,
               const float* __restrict__ W3, const float* __restrict__ B3,
               float* __restrict__ out)
{
    // XCD-aware swizzle: each XCD (bid&7 under round-robin dispatch) owns a
    // contiguous range of 128 sample-blocks x all 29 channels, so the
    // stride-29 tau gathers hit its private L2 once.
    const int bid  = blockIdx.x;
    const int xcd  = bid & 7;
    const int slot = bid >> 3;          // 0..3711 = 29*128
    const int k    = slot % NCH;
    const int br   = slot / NCH;        // 0..127
    const int b    = ((xcd << 7) | br) * 256 + threadIdx.x;

    // Per-channel weights: uniform across the wave -> scalar loads (s_load).
    const float* __restrict__ w1 = W1 + k * 256;    // [4][64]
    const float* __restrict__ b1 = B1 + k * 64;
    const float* __restrict__ w2 = W2 + k * 4096;   // [64][64]
    const float* __restrict__ b2 = B2 + k * 64;
    const float* __restrict__ w3 = W3 + k * 192;    // [64][3]
    const float* __restrict__ b3 = B3 + k * 3;

    const int idx = b * NCH + k;
    const float vtg  = tg[idx];
    const float vtl  = tl[idx];
    const float vti  = ti[idx];
    const float vmu  = mu[b];
    const float vmub = mub[b];

    // Layer-2 accumulators for both MLPs (static indexing only -> registers).
    float accd[64], accf[64];
#pragma unroll
    for (int g = 0; g < 64; ++g) { const float bv = b2[g]; accd[g] = bv; accf[g] = bv; }

    // Fused layer1+layer2: stream W2 one row (256 B contiguous, scalar) at a
    // time; h1 column j is computed in-iteration, never materialized.
#pragma unroll 2
    for (int j = 0; j < 64; ++j) {
        float a3 = b1[j];
        a3 = fmaf(vtg, w1[j],       a3);
        a3 = fmaf(vtl, w1[64 + j],  a3);
        a3 = fmaf(vti, w1[128 + j], a3);
        const float wmu = w1[192 + j];
        const float hd = elu_f(fmaf(vmu,  wmu, a3));
        const float hf = elu_f(fmaf(vmub, wmu, a3));
        const float* __restrict__ wr = w2 + j * 64;
#pragma unroll
        for (int g = 0; g < 64; ++g) {
            const float w = wr[g];
            accd[g] = fmaf(hd, w, accd[g]);
            accf[g] = fmaf(hf, w, accf[g]);
        }
    }

    // Layer 3 (fused with elu on layer-2 preactivations).
    float od0 = b3[0], od1 = b3[1], od2 = b3[2];
    float of0 = od0, of1 = od1, of2 = od2;
#pragma unroll
    for (int g = 0; g < 64; ++g) {
        const float hd = elu_f(accd[g]);
        const float hf = elu_f(accf[g]);
        const float u0 = w3[g * 3 + 0];
        const float u1 = w3[g * 3 + 1];
        const float u2 = w3[g * 3 + 2];
        od0 = fmaf(hd, u0, od0); od1 = fmaf(hd, u1, od1); od2 = fmaf(hd, u2, od2);
        of0 = fmaf(hf, u0, of0); of1 = fmaf(hf, u1, of1); of2 = fmaf(hf, u2, of2);
    }

    // softplus + softmax (direct)
    float s0 = softplus_f(od0), s1 = softplus_f(od1), s2 = softplus_f(od2);
    float mx = fmaxf(s0, fmaxf(s1, s2));
    float e0 = __expf(s0 - mx), e1 = __expf(s1 - mx), e2 = __expf(s2 - mx);
    float rs = 1.0f / (e0 + e1 + e2);
    const float ed0 = e0 * rs, ed1 = e1 * rs, ed2 = e2 * rs;

    // softplus + softmax (diffuse)
    s0 = softplus_f(of0); s1 = softplus_f(of1); s2 = softplus_f(of2);
    mx = fmaxf(s0, fmaxf(s1, s2));
    e0 = __expf(s0 - mx); e1 = __expf(s1 - mx); e2 = __expf(s2 - mx);
    rs = 1.0f / (e0 + e1 + e2);
    const float ef0 = e0 * rs, ef1 = e1 * rs, ef2 = e2 * rs;

    // Transmittances (pure f32, exact w.r.t. reference math)
    const float tau_tot = vtg + vtl + vti;
    const float t_dir = __expf(-tau_tot / (vmu  + 1e-5f));
    const float t_dif = __expf(-tau_tot / (vmub + 1e-3f));

    float4* op = reinterpret_cast<float4*>(out + (size_t)idx * 8);
    op[0] = make_float4(t_dir, t_dif, ed0, ed1);
    op[1] = make_float4(ed2, ef0, ef1, ef2);
}

extern "C" void kernel_launch(void* const* d_in, const int* in_sizes, int n_in,
                              void* d_out, int out_size, void* d_ws, size_t ws_size,
                              hipStream_t stream) {
    const float* tg  = (const float*)d_in[0];
    const float* tl  = (const float*)d_in[1];
    const float* ti  = (const float*)d_in[2];
    const float* mu  = (const float*)d_in[3];
    const float* mub = (const float*)d_in[4];
    const float* W1  = (const float*)d_in[5];
    const float* B1  = (const float*)d_in[6];
    const float* W2  = (const float*)d_in[7];
    const float* B2  = (const float*)d_in[8];
    const float* W3  = (const float*)d_in[9];
    const float* B3  = (const float*)d_in[10];
    float* out = (float*)d_out;

    const int nblk = NCH * (NB / 256);  // 29 * 1024 = 29696 blocks
    lp_kernel<<<dim3(nblk), dim3(256), 0, stream>>>(tg, tl, ti, mu, mub,
                                                    W1, B1, W2, B2, W3, B3, out);
}